// Round 12
// baseline (356.570 us; speedup 1.0000x reference)
//
#include <hip/hip_runtime.h>
#include <hip/hip_bf16.h>

// GraphConv x2 (DGL norm='both'), N=100000, E=3.2M, 128->128(relu)->64.
// Round 12: overhead pass. NCHUNK=64 (halved hist/cum traffic), place2 NS=2
// (38MB edge reads, XCD-pinned ranges), transpose merged into scan2 launch.
// Gathers confirmed at the random-line L2-miss-path plateau (~3.6TB/s) —
// round 11's 2x MLP was null, so they are left unchanged.

typedef unsigned short u16;
typedef unsigned int   u32;
using bf16x8 = __attribute__((ext_vector_type(8))) short;
using f32x4  = __attribute__((ext_vector_type(4))) float;

__device__ __forceinline__ float bfu2f(u16 u) {
    union { unsigned int i; float f; } c; c.i = ((unsigned int)u) << 16; return c.f;
}
__device__ __forceinline__ u16 f2bfu(float f) {
    union { float fv; unsigned int i; } c; c.fv = f;
    unsigned int x = c.i;
    x += 0x7fffu + ((x >> 16) & 1u);   // RNE (finite values only)
    return (u16)(x >> 16);
}
__device__ __forceinline__ void acc8(float* a, uint4 u) {
    union { u32 i; float f; } c;
    c.i = u.x << 16;         a[0] += c.f;
    c.i = u.x & 0xffff0000u; a[1] += c.f;
    c.i = u.y << 16;         a[2] += c.f;
    c.i = u.y & 0xffff0000u; a[3] += c.f;
    c.i = u.z << 16;         a[4] += c.f;
    c.i = u.z & 0xffff0000u; a[5] += c.f;
    c.i = u.w << 16;         a[6] += c.f;
    c.i = u.w & 0xffff0000u; a[7] += c.f;
}

constexpr int NCHUNK = 64;

// Per-chunk full-range histogram, byte-packed u32 in LDS (100KB).
// Blocks 0..63: dst chunk -> pd ; 64..127: src chunk -> ps.
__global__ __launch_bounds__(1024) void hist8_kernel(const int* __restrict__ src,
    const int* __restrict__ dst, int E, int M, u32* __restrict__ pd, u32* __restrict__ ps)
{
    __shared__ u32 h[25088];
    const int W = (M + 3) >> 2;
    const bool isSrc = blockIdx.x >= NCHUNK;
    const int c = isSrc ? (blockIdx.x - NCHUNK) : blockIdx.x;
    const int* vals = isSrc ? src : dst;
    u32* out = (isSrc ? ps : pd) + (size_t)c * W;
    for (int k = threadIdx.x; k < W; k += 1024) h[k] = 0;
    __syncthreads();
    const int ebeg = (int)((long long)c * E / NCHUNK);
    const int eend = (int)((long long)(c + 1) * E / NCHUNK);
    for (int i = ebeg + threadIdx.x; i < eend; i += 1024) {
        int v = vals[i];
        atomicAdd(&h[v >> 2], 1u << ((v & 3) * 8));
    }
    __syncthreads();
    for (int k = threadIdx.x; k < W; k += 1024) out[k] = h[k];
}

// Per packed word: cum over chunks, norms, deg; fused per-1024-node block sums.
__global__ __launch_bounds__(256) void cumreduce_kernel(const u32* __restrict__ pd,
    const u32* __restrict__ ps, u32* __restrict__ cum, int* __restrict__ deg_in,
    float* __restrict__ ns, float* __restrict__ nd, int* __restrict__ bsum, int M)
{
    __shared__ int sh[256];
    const int W = (M + 3) >> 2;
    int w = blockIdx.x * 256 + threadIdx.x;
    u32 run = 0, so = 0;
    if (w < W) {
        for (int c = 0; c < NCHUNK; ++c) {
            cum[(size_t)c * W + w] = run;
            run += pd[(size_t)c * W + w];
        }
        for (int c = 0; c < NCHUNK; ++c) so += ps[(size_t)c * W + w];
        #pragma unroll
        for (int j = 0; j < 4; ++j) {
            int d = w * 4 + j;
            if (d < M) {
                int din  = (run >> (j * 8)) & 255;
                int dout = (so  >> (j * 8)) & 255;
                deg_in[d] = din;
                nd[d] = rsqrtf((float)max(din, 1));
                ns[d] = rsqrtf((float)max(dout, 1));
            }
        }
    }
    sh[threadIdx.x] = (run & 255) + ((run >> 8) & 255) + ((run >> 16) & 255) + (run >> 24);
    __syncthreads();
    for (int off = 128; off > 0; off >>= 1) {
        if (threadIdx.x < off) sh[threadIdx.x] += sh[threadIdx.x + off];
        __syncthreads();
    }
    if (threadIdx.x == 0) bsum[blockIdx.x] = sh[0];
}

// Block 0: exclusive scan of bsum -> boff (+ row_ptr[M]).
// Blocks 1..24: W0/W1 -> bf16 transposed Wt0/Wt1.
__global__ __launch_bounds__(256) void scan2_transpose_kernel(
    const int* __restrict__ bsum, int* __restrict__ boff, int NB,
    int* __restrict__ row_ptr, int M,
    const float* __restrict__ W0, const float* __restrict__ W1,
    u16* __restrict__ Wt0, u16* __restrict__ Wt1)
{
    if (blockIdx.x == 0) {
        __shared__ int sh[256];
        const int t = threadIdx.x;
        sh[t] = (t < NB) ? bsum[t] : 0;
        __syncthreads();
        for (int off = 1; off < 256; off <<= 1) {
            int v = (t >= off) ? sh[t - off] : 0;
            __syncthreads();
            sh[t] += v;
            __syncthreads();
        }
        if (t < NB) boff[t] = (t == 0) ? 0 : sh[t - 1];
        if (t == 0) row_ptr[M] = sh[255];
    } else {
        __shared__ float tt[32][33];
        int b = blockIdx.x - 1;
        const float* in; u16* out; int K, N, tk, tn;
        if (b < 16) { in = W0; out = Wt0; K = 128; N = 128; tk = b >> 2; tn = b & 3; }
        else { b -= 16; in = W1; out = Wt1; K = 128; N = 64; tk = b >> 1; tn = b & 1; }
        int tx = threadIdx.x & 31, ty = threadIdx.x >> 5;
        int k0 = tk * 32, n0 = tn * 32;
        #pragma unroll
        for (int i = 0; i < 4; ++i)
            tt[ty + 8 * i][tx] = in[(size_t)(k0 + ty + 8 * i) * N + n0 + tx];
        __syncthreads();
        #pragma unroll
        for (int i = 0; i < 4; ++i)
            out[(size_t)(n0 + ty + 8 * i) * K + k0 + tx] = f2bfu(tt[tx][ty + 8 * i]);
    }
}

__global__ __launch_bounds__(256) void scan3_kernel(const int* __restrict__ deg,
    const int* __restrict__ boff, int* __restrict__ row_ptr, int M)
{
    __shared__ int sh[256];
    const int base = blockIdx.x * 1024;
    const int idx0 = base + threadIdx.x * 4;
    int v[4]; int s = 0;
    #pragma unroll
    for (int j = 0; j < 4; ++j) {
        int i = idx0 + j;
        v[j] = (i < M) ? deg[i] : 0;
        s += v[j];
    }
    sh[threadIdx.x] = s;
    __syncthreads();
    for (int off = 1; off < 256; off <<= 1) {
        int t = (threadIdx.x >= off) ? sh[threadIdx.x - off] : 0;
        __syncthreads();
        sh[threadIdx.x] += t;
        __syncthreads();
    }
    int run = boff[blockIdx.x] + ((threadIdx.x == 0) ? 0 : sh[threadIdx.x - 1]);
    #pragma unroll
    for (int j = 0; j < 4; ++j) {
        int i = idx0 + j;
        if (i < M) { row_ptr[i] = run; run += v[j]; }
    }
}

// Atomic-free CSC place, NS=2 ranges (50KB LDS ranks). XCD-pinned:
// r = (bid>>2)&1 (XCDs 0-3 -> range 0, 4-7 -> range 1, via bid%8 heuristic);
// c = ((bid>>3)<<2)|(bid&3). Bijective for 128 blocks.
constexpr int NS = 2;
__global__ __launch_bounds__(256) void place2_kernel(const int* __restrict__ src,
    const int* __restrict__ dst, int E, int M, const int* __restrict__ row_ptr,
    const u32* __restrict__ cum, int* __restrict__ eidx)
{
    __shared__ u32 rank[12544];
    const int W = (M + 3) >> 2;
    const int bid = blockIdx.x;
    const int r = (bid >> 2) & 1;
    const int c = ((bid >> 3) << 2) | (bid & 3);
    const int span = (M + NS - 1) / NS;
    const int lo = r * span;
    const int hi = min(lo + span, M);
    const int wspan = (span + 3) >> 2;
    for (int k = threadIdx.x; k < wspan; k += 256) rank[k] = 0;
    __syncthreads();
    const int ebeg = (int)((long long)c * E / NCHUNK);
    const int eend = (int)((long long)(c + 1) * E / NCHUNK);
    const u32* cumc = cum + (size_t)c * W;
    for (int i = ebeg + threadIdx.x; i < eend; i += 256) {
        int d = dst[i];
        if (d >= lo && d < hi) {
            int dl = d - lo;
            u32 old = atomicAdd(&rank[dl >> 2], 1u << ((dl & 3) * 8));
            int rk   = (old >> ((dl & 3) * 8)) & 255;
            int base = (cumc[d >> 2] >> ((d & 3) * 8)) & 255;
            eidx[row_ptr[d] + base + rk] = src[i];
        }
    }
}

// MFMA bf16 GEMM (unchanged).
template<int NOUT, bool XF32>
__global__ __launch_bounds__(256) void mfma_gemm_kernel(const void* __restrict__ xin,
    const u16* __restrict__ Wt, const float* __restrict__ rowscale,
    u16* __restrict__ out, int M)
{
    constexpr int CPW = NOUT / 64;
    __shared__ __align__(16) u16 xs[64 * 128];
    __shared__ __align__(16) u16 wl[NOUT * 128];

    const int tid = threadIdx.x;
    const int w = tid >> 6;
    const int l = tid & 63;
    const int ln = l & 15, g = l >> 4;
    const int rbase = blockIdx.x * 64;

    for (int c = tid; c < NOUT * 16; c += 256) {
        int n = c >> 4, s = c & 15;
        uint4 v = *(const uint4*)(Wt + (size_t)n * 128 + s * 8);
        *(uint4*)(&wl[n * 128 + ((s * 8) ^ ((n & 7) << 3))]) = v;
    }
    if (XF32) {
        const float* xf = (const float*)xin;
        for (int c = tid; c < 64 * 16; c += 256) {
            int r = c >> 4, s = c & 15;
            int row = rbase + r;
            uint4 p = make_uint4(0, 0, 0, 0);
            if (row < M) {
                float sc = rowscale[row];
                float4 v0 = *(const float4*)(xf + (size_t)row * 128 + s * 8);
                float4 v1 = *(const float4*)(xf + (size_t)row * 128 + s * 8 + 4);
                p.x = ((u32)f2bfu(v0.y * sc) << 16) | f2bfu(v0.x * sc);
                p.y = ((u32)f2bfu(v0.w * sc) << 16) | f2bfu(v0.z * sc);
                p.z = ((u32)f2bfu(v1.y * sc) << 16) | f2bfu(v1.x * sc);
                p.w = ((u32)f2bfu(v1.w * sc) << 16) | f2bfu(v1.z * sc);
            }
            *(uint4*)(&xs[r * 128 + ((s * 8) ^ ((r & 7) << 3))]) = p;
        }
    } else {
        const u16* xb = (const u16*)xin;
        for (int c = tid; c < 64 * 16; c += 256) {
            int r = c >> 4, s = c & 15;
            int row = rbase + r;
            uint4 v = make_uint4(0, 0, 0, 0);
            if (row < M) v = *(const uint4*)(xb + (size_t)row * 128 + s * 8);
            *(uint4*)(&xs[r * 128 + ((s * 8) ^ ((r & 7) << 3))]) = v;
        }
    }
    __syncthreads();

    bf16x8 bfrag[CPW][4];
    #pragma unroll
    for (int cf = 0; cf < CPW; ++cf) {
        int n = (w * CPW + cf) * 16 + ln;
        #pragma unroll
        for (int ks = 0; ks < 4; ++ks) {
            int koff = ks * 32 + g * 8;
            bfrag[cf][ks] = *(const bf16x8*)(&wl[n * 128 + (koff ^ ((n & 7) << 3))]);
        }
    }

    f32x4 acc[4][CPW];
    #pragma unroll
    for (int m = 0; m < 4; ++m)
        #pragma unroll
        for (int cf = 0; cf < CPW; ++cf)
            acc[m][cf] = (f32x4){0.f, 0.f, 0.f, 0.f};

    #pragma unroll
    for (int m = 0; m < 4; ++m) {
        int r = m * 16 + ln;
        #pragma unroll
        for (int ks = 0; ks < 4; ++ks) {
            int koff = ks * 32 + g * 8;
            bf16x8 a = *(const bf16x8*)(&xs[r * 128 + (koff ^ ((ln & 7) << 3))]);
            #pragma unroll
            for (int cf = 0; cf < CPW; ++cf)
                acc[m][cf] = __builtin_amdgcn_mfma_f32_16x16x32_bf16(
                    a, bfrag[cf][ks], acc[m][cf], 0, 0, 0);
        }
    }

    #pragma unroll
    for (int m = 0; m < 4; ++m) {
        int row = rbase + m * 16 + g * 4;
        #pragma unroll
        for (int j = 0; j < 4; ++j) {
            if (row + j < M) {
                #pragma unroll
                for (int cf = 0; cf < CPW; ++cf) {
                    int col = (w * CPW + cf) * 16 + ln;
                    out[(size_t)(row + j) * NOUT + col] = f2bfu(acc[m][cf][j]);
                }
            }
        }
    }
}

// Gather F=128 (unchanged): 16 lanes/row uint4, 4 edges/step, unroll x4.
__global__ __launch_bounds__(256) void gather128_kernel(const int* __restrict__ row_ptr,
    const int* __restrict__ eidx, const u16* __restrict__ h,
    const float* __restrict__ nd, const float* __restrict__ nsc,
    const float* __restrict__ b, u16* __restrict__ out, int M)
{
    const int wave = (blockIdx.x * 256 + threadIdx.x) >> 6;
    const int lane = threadIdx.x & 63;
    if (wave >= M) return;
    const int beg = row_ptr[wave];
    const int end = row_ptr[wave + 1];
    const int q = lane >> 4;
    const int l = lane & 15;
    float a[8] = {};
    for (int jb = beg; jb < end; jb += 64) {
        const int cnt = min(64, end - jb);
        int myidx = (jb + lane < end) ? eidx[jb + lane] : 0;
        int k = 0;
        for (; k + 16 <= cnt; k += 16) {
            int s0 = __shfl(myidx, k + 0 + q);
            int s1 = __shfl(myidx, k + 4 + q);
            int s2 = __shfl(myidx, k + 8 + q);
            int s3 = __shfl(myidx, k + 12 + q);
            uint4 u0 = *(const uint4*)(h + (size_t)s0 * 128 + l * 8);
            uint4 u1 = *(const uint4*)(h + (size_t)s1 * 128 + l * 8);
            uint4 u2 = *(const uint4*)(h + (size_t)s2 * 128 + l * 8);
            uint4 u3 = *(const uint4*)(h + (size_t)s3 * 128 + l * 8);
            acc8(a, u0); acc8(a, u1); acc8(a, u2); acc8(a, u3);
        }
        for (; k < cnt; k += 4) {
            int kk = k + q;
            int s = __shfl(myidx, (kk < cnt) ? kk : 0);
            uint4 u = *(const uint4*)(h + (size_t)s * 128 + l * 8);
            if (kk < cnt) acc8(a, u);
        }
    }
    #pragma unroll
    for (int i = 0; i < 8; ++i) {
        a[i] += __shfl_xor(a[i], 32);
        a[i] += __shfl_xor(a[i], 16);
    }
    if (q == 0) {
        const float s = nd[wave];
        const float sn = nsc[wave];
        uint4 o;
        u32 w0, w1;
        w0 = f2bfu(fmaxf(fmaf(a[0], s, b[l * 8 + 0]), 0.f) * sn);
        w1 = f2bfu(fmaxf(fmaf(a[1], s, b[l * 8 + 1]), 0.f) * sn);
        o.x = (w1 << 16) | w0;
        w0 = f2bfu(fmaxf(fmaf(a[2], s, b[l * 8 + 2]), 0.f) * sn);
        w1 = f2bfu(fmaxf(fmaf(a[3], s, b[l * 8 + 3]), 0.f) * sn);
        o.y = (w1 << 16) | w0;
        w0 = f2bfu(fmaxf(fmaf(a[4], s, b[l * 8 + 4]), 0.f) * sn);
        w1 = f2bfu(fmaxf(fmaf(a[5], s, b[l * 8 + 5]), 0.f) * sn);
        o.z = (w1 << 16) | w0;
        w0 = f2bfu(fmaxf(fmaf(a[6], s, b[l * 8 + 6]), 0.f) * sn);
        w1 = f2bfu(fmaxf(fmaf(a[7], s, b[l * 8 + 7]), 0.f) * sn);
        o.w = (w1 << 16) | w0;
        *(uint4*)(out + (size_t)wave * 128 + l * 8) = o;
    }
}

// Gather F=64 (unchanged): 8 lanes/row uint4, 8 edges/step, unroll x4.
__global__ __launch_bounds__(256) void gather64_kernel(const int* __restrict__ row_ptr,
    const int* __restrict__ eidx, const u16* __restrict__ h,
    const float* __restrict__ nd, const float* __restrict__ b,
    float* __restrict__ out, int M)
{
    const int wave = (blockIdx.x * 256 + threadIdx.x) >> 6;
    const int lane = threadIdx.x & 63;
    if (wave >= M) return;
    const int beg = row_ptr[wave];
    const int end = row_ptr[wave + 1];
    const int o = lane >> 3;
    const int l = lane & 7;
    float a[8] = {};
    for (int jb = beg; jb < end; jb += 64) {
        const int cnt = min(64, end - jb);
        int myidx = (jb + lane < end) ? eidx[jb + lane] : 0;
        int k = 0;
        for (; k + 32 <= cnt; k += 32) {
            int s0 = __shfl(myidx, k + 0 + o);
            int s1 = __shfl(myidx, k + 8 + o);
            int s2 = __shfl(myidx, k + 16 + o);
            int s3 = __shfl(myidx, k + 24 + o);
            uint4 u0 = *(const uint4*)(h + (size_t)s0 * 64 + l * 8);
            uint4 u1 = *(const uint4*)(h + (size_t)s1 * 64 + l * 8);
            uint4 u2 = *(const uint4*)(h + (size_t)s2 * 64 + l * 8);
            uint4 u3 = *(const uint4*)(h + (size_t)s3 * 64 + l * 8);
            acc8(a, u0); acc8(a, u1); acc8(a, u2); acc8(a, u3);
        }
        for (; k < cnt; k += 8) {
            int kk = k + o;
            int s = __shfl(myidx, (kk < cnt) ? kk : 0);
            uint4 u = *(const uint4*)(h + (size_t)s * 64 + l * 8);
            if (kk < cnt) acc8(a, u);
        }
    }
    #pragma unroll
    for (int i = 0; i < 8; ++i) {
        a[i] += __shfl_xor(a[i], 32);
        a[i] += __shfl_xor(a[i], 16);
        a[i] += __shfl_xor(a[i], 8);
    }
    if (o == 0) {
        const float s = nd[wave];
        float4 o0, o1;
        o0.x = fmaf(a[0], s, b[l * 8 + 0]);
        o0.y = fmaf(a[1], s, b[l * 8 + 1]);
        o0.z = fmaf(a[2], s, b[l * 8 + 2]);
        o0.w = fmaf(a[3], s, b[l * 8 + 3]);
        o1.x = fmaf(a[4], s, b[l * 8 + 4]);
        o1.y = fmaf(a[5], s, b[l * 8 + 5]);
        o1.z = fmaf(a[6], s, b[l * 8 + 6]);
        o1.w = fmaf(a[7], s, b[l * 8 + 7]);
        *(float4*)(out + (size_t)wave * 64 + l * 8) = o0;
        *(float4*)(out + (size_t)wave * 64 + l * 8 + 4) = o1;
    }
}

extern "C" void kernel_launch(void* const* d_in, const int* in_sizes, int n_in,
                              void* d_out, int out_size, void* d_ws, size_t ws_size,
                              hipStream_t stream) {
    const float* x  = (const float*)d_in[0];   // [M,128] f32
    const int*   ei = (const int*)d_in[1];     // [2,E] int32
    const float* W0 = (const float*)d_in[2];   // [128,128]
    const float* b0 = (const float*)d_in[3];   // [128]
    const float* W1 = (const float*)d_in[4];   // [128,64]
    const float* b1 = (const float*)d_in[5];   // [64]

    const int M = in_sizes[0] / 128;     // 100000
    const int E = in_sizes[1] / 2;       // 3200000
    const int* src = ei;
    const int* dst = ei + E;
    const int W = (M + 3) >> 2;

    char* ws = (char*)d_ws;
    size_t off = 0;
    auto alloc = [&](size_t bytes) {
        void* p = ws + off; off += (bytes + 255) & ~(size_t)255; return p;
    };
    int*   deg_in   = (int*)  alloc((size_t)M * 4);
    float* norm_src = (float*)alloc((size_t)M * 4);
    float* norm_dst = (float*)alloc((size_t)M * 4);
    int*   row_ptr  = (int*)  alloc((size_t)(M + 1) * 4);
    int*   bsum     = (int*)  alloc(256 * 4);
    int*   boff     = (int*)  alloc(256 * 4);
    u16*   Wt0      = (u16*)  alloc(128 * 128 * 2);
    u16*   Wt1      = (u16*)  alloc(64 * 128 * 2);
    int*   eidx     = (int*)  alloc((size_t)E * 4);        // 12.8 MB
    u16*   hbuf     = (u16*)  alloc((size_t)M * 128 * 2);  // 25.6 MB: h0 -> h1
    u16*   out0b    = (u16*)  alloc((size_t)M * 128 * 2);  // 25.6 MB: out0 (bf16, *ns)

    // pd/ps/cum alias hbuf (19.2MB @ NCHUNK=64); dead before gemm0 writes hbuf.
    u32* pd  = (u32*)hbuf;
    u32* ps  = pd + (size_t)NCHUNK * W;
    u32* cum = ps + (size_t)NCHUNK * W;

    const int NB = (M + 1023) / 1024;   // 98

    // graph preprocessing (deterministic; no global atomics)
    hist8_kernel<<<2 * NCHUNK, 1024, 0, stream>>>(src, dst, E, M, pd, ps);
    cumreduce_kernel<<<NB, 256, 0, stream>>>(pd, ps, cum, deg_in,
        norm_src, norm_dst, bsum, M);
    scan2_transpose_kernel<<<25, 256, 0, stream>>>(bsum, boff, NB, row_ptr, M,
        W0, W1, Wt0, Wt1);
    scan3_kernel<<<NB, 256, 0, stream>>>(deg_in, boff, row_ptr, M);
    place2_kernel<<<NS * NCHUNK, 256, 0, stream>>>(src, dst, E, M, row_ptr, cum, eidx);

    const int GB = (M + 63) / 64;
    // layer 0: h0 = bf16((x*ns)@W0) ; out0b = bf16(relu(gather(h0)*nd + b0) * ns)
    mfma_gemm_kernel<128, true><<<GB, 256, 0, stream>>>(x, Wt0, norm_src, hbuf, M);
    gather128_kernel<<<(M * 64 + 255) / 256, 256, 0, stream>>>(
        row_ptr, eidx, hbuf, norm_dst, norm_src, b0, out0b, M);

    // layer 1: h1 = bf16(out0b@W1) ; out = gather(h1)*nd + b1
    mfma_gemm_kernel<64, false><<<GB, 256, 0, stream>>>(out0b, Wt1, nullptr, hbuf, M);
    gather64_kernel<<<(M * 64 + 255) / 256, 256, 0, stream>>>(
        row_ptr, eidx, hbuf, norm_dst, b1, (float*)d_out, M);
}

// Round 13
// 305.199 us; speedup vs baseline: 1.1683x; 1.1683x over previous
//
#include <hip/hip_runtime.h>
#include <hip/hip_bf16.h>

// GraphConv x2 (DGL norm='both'), N=100000, E=3.2M, 128->128(relu)->64.
// Round 13: REVERT round-12 regression (place2 NS=2 under-subscribed 128 blocks
// + 6.4MB write window > L2 -> 9.4x write amp, 132us). Back to round-11 config:
// NCHUNK=128, place2 NS=4 (512 blocks, 25KB LDS, 3.2MB XCD-pinned windows).
// Keeps round-12's scan2+transpose launch merge. Gathers remain at the
// random-line fetch plateau (round-11 MLP null confirmed).

typedef unsigned short u16;
typedef unsigned int   u32;
using bf16x8 = __attribute__((ext_vector_type(8))) short;
using f32x4  = __attribute__((ext_vector_type(4))) float;

__device__ __forceinline__ float bfu2f(u16 u) {
    union { unsigned int i; float f; } c; c.i = ((unsigned int)u) << 16; return c.f;
}
__device__ __forceinline__ u16 f2bfu(float f) {
    union { float fv; unsigned int i; } c; c.fv = f;
    unsigned int x = c.i;
    x += 0x7fffu + ((x >> 16) & 1u);   // RNE (finite values only)
    return (u16)(x >> 16);
}
__device__ __forceinline__ void acc8(float* a, uint4 u) {
    union { u32 i; float f; } c;
    c.i = u.x << 16;         a[0] += c.f;
    c.i = u.x & 0xffff0000u; a[1] += c.f;
    c.i = u.y << 16;         a[2] += c.f;
    c.i = u.y & 0xffff0000u; a[3] += c.f;
    c.i = u.z << 16;         a[4] += c.f;
    c.i = u.z & 0xffff0000u; a[5] += c.f;
    c.i = u.w << 16;         a[6] += c.f;
    c.i = u.w & 0xffff0000u; a[7] += c.f;
}

constexpr int NCHUNK = 128;

// Per-chunk full-range histogram, byte-packed u32 in LDS (100KB).
__global__ __launch_bounds__(1024) void hist8_kernel(const int* __restrict__ src,
    const int* __restrict__ dst, int E, int M, u32* __restrict__ pd, u32* __restrict__ ps)
{
    __shared__ u32 h[25088];
    const int W = (M + 3) >> 2;
    const bool isSrc = blockIdx.x >= NCHUNK;
    const int c = isSrc ? (blockIdx.x - NCHUNK) : blockIdx.x;
    const int* vals = isSrc ? src : dst;
    u32* out = (isSrc ? ps : pd) + (size_t)c * W;
    for (int k = threadIdx.x; k < W; k += 1024) h[k] = 0;
    __syncthreads();
    const int ebeg = (int)((long long)c * E / NCHUNK);
    const int eend = (int)((long long)(c + 1) * E / NCHUNK);
    for (int i = ebeg + threadIdx.x; i < eend; i += 1024) {
        int v = vals[i];
        atomicAdd(&h[v >> 2], 1u << ((v & 3) * 8));
    }
    __syncthreads();
    for (int k = threadIdx.x; k < W; k += 1024) out[k] = h[k];
}

// Per packed word: cum over chunks, norms, deg; fused per-1024-node block sums.
__global__ __launch_bounds__(256) void cumreduce_kernel(const u32* __restrict__ pd,
    const u32* __restrict__ ps, u32* __restrict__ cum, int* __restrict__ deg_in,
    float* __restrict__ ns, float* __restrict__ nd, int* __restrict__ bsum, int M)
{
    __shared__ int sh[256];
    const int W = (M + 3) >> 2;
    int w = blockIdx.x * 256 + threadIdx.x;
    u32 run = 0, so = 0;
    if (w < W) {
        for (int c = 0; c < NCHUNK; ++c) {
            cum[(size_t)c * W + w] = run;
            run += pd[(size_t)c * W + w];
        }
        for (int c = 0; c < NCHUNK; ++c) so += ps[(size_t)c * W + w];
        #pragma unroll
        for (int j = 0; j < 4; ++j) {
            int d = w * 4 + j;
            if (d < M) {
                int din  = (run >> (j * 8)) & 255;
                int dout = (so  >> (j * 8)) & 255;
                deg_in[d] = din;
                nd[d] = rsqrtf((float)max(din, 1));
                ns[d] = rsqrtf((float)max(dout, 1));
            }
        }
    }
    sh[threadIdx.x] = (run & 255) + ((run >> 8) & 255) + ((run >> 16) & 255) + (run >> 24);
    __syncthreads();
    for (int off = 128; off > 0; off >>= 1) {
        if (threadIdx.x < off) sh[threadIdx.x] += sh[threadIdx.x + off];
        __syncthreads();
    }
    if (threadIdx.x == 0) bsum[blockIdx.x] = sh[0];
}

// Block 0: exclusive scan of bsum -> boff (+ row_ptr[M]).
// Blocks 1..24: W0/W1 -> bf16 transposed Wt0/Wt1.
__global__ __launch_bounds__(256) void scan2_transpose_kernel(
    const int* __restrict__ bsum, int* __restrict__ boff, int NB,
    int* __restrict__ row_ptr, int M,
    const float* __restrict__ W0, const float* __restrict__ W1,
    u16* __restrict__ Wt0, u16* __restrict__ Wt1)
{
    if (blockIdx.x == 0) {
        __shared__ int sh[256];
        const int t = threadIdx.x;
        sh[t] = (t < NB) ? bsum[t] : 0;
        __syncthreads();
        for (int off = 1; off < 256; off <<= 1) {
            int v = (t >= off) ? sh[t - off] : 0;
            __syncthreads();
            sh[t] += v;
            __syncthreads();
        }
        if (t < NB) boff[t] = (t == 0) ? 0 : sh[t - 1];
        if (t == 0) row_ptr[M] = sh[255];
    } else {
        __shared__ float tt[32][33];
        int b = blockIdx.x - 1;
        const float* in; u16* out; int K, N, tk, tn;
        if (b < 16) { in = W0; out = Wt0; K = 128; N = 128; tk = b >> 2; tn = b & 3; }
        else { b -= 16; in = W1; out = Wt1; K = 128; N = 64; tk = b >> 1; tn = b & 1; }
        int tx = threadIdx.x & 31, ty = threadIdx.x >> 5;
        int k0 = tk * 32, n0 = tn * 32;
        #pragma unroll
        for (int i = 0; i < 4; ++i)
            tt[ty + 8 * i][tx] = in[(size_t)(k0 + ty + 8 * i) * N + n0 + tx];
        __syncthreads();
        #pragma unroll
        for (int i = 0; i < 4; ++i)
            out[(size_t)(n0 + ty + 8 * i) * K + k0 + tx] = f2bfu(tt[tx][ty + 8 * i]);
    }
}

__global__ __launch_bounds__(256) void scan3_kernel(const int* __restrict__ deg,
    const int* __restrict__ boff, int* __restrict__ row_ptr, int M)
{
    __shared__ int sh[256];
    const int base = blockIdx.x * 1024;
    const int idx0 = base + threadIdx.x * 4;
    int v[4]; int s = 0;
    #pragma unroll
    for (int j = 0; j < 4; ++j) {
        int i = idx0 + j;
        v[j] = (i < M) ? deg[i] : 0;
        s += v[j];
    }
    sh[threadIdx.x] = s;
    __syncthreads();
    for (int off = 1; off < 256; off <<= 1) {
        int t = (threadIdx.x >= off) ? sh[threadIdx.x - off] : 0;
        __syncthreads();
        sh[threadIdx.x] += t;
        __syncthreads();
    }
    int run = boff[blockIdx.x] + ((threadIdx.x == 0) ? 0 : sh[threadIdx.x - 1]);
    #pragma unroll
    for (int j = 0; j < 4; ++j) {
        int i = idx0 + j;
        if (i < M) { row_ptr[i] = run; run += v[j]; }
    }
}

// Atomic-free CSC place, NS=4 ranges. r = (bid&7)>>1 -> XCD-pinned 3.2MB
// eidx write windows (bid%8 round-robin heuristic); bijective over 512 blocks.
constexpr int NS = 4;
__global__ __launch_bounds__(256) void place2_kernel(const int* __restrict__ src,
    const int* __restrict__ dst, int E, int M, const int* __restrict__ row_ptr,
    const u32* __restrict__ cum, int* __restrict__ eidx)
{
    __shared__ u32 rank[6272];
    const int W = (M + 3) >> 2;
    const int bid = blockIdx.x;
    const int r = (bid & 7) >> 1;
    const int c = ((bid >> 3) << 1) | (bid & 1);
    const int span = (M + NS - 1) / NS;
    const int lo = r * span;
    const int hi = min(lo + span, M);
    const int wspan = (span + 3) >> 2;
    for (int k = threadIdx.x; k < wspan; k += 256) rank[k] = 0;
    __syncthreads();
    const int ebeg = (int)((long long)c * E / NCHUNK);
    const int eend = (int)((long long)(c + 1) * E / NCHUNK);
    const u32* cumc = cum + (size_t)c * W;
    for (int i = ebeg + threadIdx.x; i < eend; i += 256) {
        int d = dst[i];
        if (d >= lo && d < hi) {
            int dl = d - lo;
            u32 old = atomicAdd(&rank[dl >> 2], 1u << ((dl & 3) * 8));
            int rk   = (old >> ((dl & 3) * 8)) & 255;
            int base = (cumc[d >> 2] >> ((d & 3) * 8)) & 255;
            eidx[row_ptr[d] + base + rk] = src[i];
        }
    }
}

// MFMA bf16 GEMM (unchanged).
template<int NOUT, bool XF32>
__global__ __launch_bounds__(256) void mfma_gemm_kernel(const void* __restrict__ xin,
    const u16* __restrict__ Wt, const float* __restrict__ rowscale,
    u16* __restrict__ out, int M)
{
    constexpr int CPW = NOUT / 64;
    __shared__ __align__(16) u16 xs[64 * 128];
    __shared__ __align__(16) u16 wl[NOUT * 128];

    const int tid = threadIdx.x;
    const int w = tid >> 6;
    const int l = tid & 63;
    const int ln = l & 15, g = l >> 4;
    const int rbase = blockIdx.x * 64;

    for (int c = tid; c < NOUT * 16; c += 256) {
        int n = c >> 4, s = c & 15;
        uint4 v = *(const uint4*)(Wt + (size_t)n * 128 + s * 8);
        *(uint4*)(&wl[n * 128 + ((s * 8) ^ ((n & 7) << 3))]) = v;
    }
    if (XF32) {
        const float* xf = (const float*)xin;
        for (int c = tid; c < 64 * 16; c += 256) {
            int r = c >> 4, s = c & 15;
            int row = rbase + r;
            uint4 p = make_uint4(0, 0, 0, 0);
            if (row < M) {
                float sc = rowscale[row];
                float4 v0 = *(const float4*)(xf + (size_t)row * 128 + s * 8);
                float4 v1 = *(const float4*)(xf + (size_t)row * 128 + s * 8 + 4);
                p.x = ((u32)f2bfu(v0.y * sc) << 16) | f2bfu(v0.x * sc);
                p.y = ((u32)f2bfu(v0.w * sc) << 16) | f2bfu(v0.z * sc);
                p.z = ((u32)f2bfu(v1.y * sc) << 16) | f2bfu(v1.x * sc);
                p.w = ((u32)f2bfu(v1.w * sc) << 16) | f2bfu(v1.z * sc);
            }
            *(uint4*)(&xs[r * 128 + ((s * 8) ^ ((r & 7) << 3))]) = p;
        }
    } else {
        const u16* xb = (const u16*)xin;
        for (int c = tid; c < 64 * 16; c += 256) {
            int r = c >> 4, s = c & 15;
            int row = rbase + r;
            uint4 v = make_uint4(0, 0, 0, 0);
            if (row < M) v = *(const uint4*)(xb + (size_t)row * 128 + s * 8);
            *(uint4*)(&xs[r * 128 + ((s * 8) ^ ((r & 7) << 3))]) = v;
        }
    }
    __syncthreads();

    bf16x8 bfrag[CPW][4];
    #pragma unroll
    for (int cf = 0; cf < CPW; ++cf) {
        int n = (w * CPW + cf) * 16 + ln;
        #pragma unroll
        for (int ks = 0; ks < 4; ++ks) {
            int koff = ks * 32 + g * 8;
            bfrag[cf][ks] = *(const bf16x8*)(&wl[n * 128 + (koff ^ ((n & 7) << 3))]);
        }
    }

    f32x4 acc[4][CPW];
    #pragma unroll
    for (int m = 0; m < 4; ++m)
        #pragma unroll
        for (int cf = 0; cf < CPW; ++cf)
            acc[m][cf] = (f32x4){0.f, 0.f, 0.f, 0.f};

    #pragma unroll
    for (int m = 0; m < 4; ++m) {
        int r = m * 16 + ln;
        #pragma unroll
        for (int ks = 0; ks < 4; ++ks) {
            int koff = ks * 32 + g * 8;
            bf16x8 a = *(const bf16x8*)(&xs[r * 128 + (koff ^ ((ln & 7) << 3))]);
            #pragma unroll
            for (int cf = 0; cf < CPW; ++cf)
                acc[m][cf] = __builtin_amdgcn_mfma_f32_16x16x32_bf16(
                    a, bfrag[cf][ks], acc[m][cf], 0, 0, 0);
        }
    }

    #pragma unroll
    for (int m = 0; m < 4; ++m) {
        int row = rbase + m * 16 + g * 4;
        #pragma unroll
        for (int j = 0; j < 4; ++j) {
            if (row + j < M) {
                #pragma unroll
                for (int cf = 0; cf < CPW; ++cf) {
                    int col = (w * CPW + cf) * 16 + ln;
                    out[(size_t)(row + j) * NOUT + col] = f2bfu(acc[m][cf][j]);
                }
            }
        }
    }
}

// Gather F=128: 16 lanes/row uint4, 4 edges/step, unroll x4.
__global__ __launch_bounds__(256) void gather128_kernel(const int* __restrict__ row_ptr,
    const int* __restrict__ eidx, const u16* __restrict__ h,
    const float* __restrict__ nd, const float* __restrict__ nsc,
    const float* __restrict__ b, u16* __restrict__ out, int M)
{
    const int wave = (blockIdx.x * 256 + threadIdx.x) >> 6;
    const int lane = threadIdx.x & 63;
    if (wave >= M) return;
    const int beg = row_ptr[wave];
    const int end = row_ptr[wave + 1];
    const int q = lane >> 4;
    const int l = lane & 15;
    float a[8] = {};
    for (int jb = beg; jb < end; jb += 64) {
        const int cnt = min(64, end - jb);
        int myidx = (jb + lane < end) ? eidx[jb + lane] : 0;
        int k = 0;
        for (; k + 16 <= cnt; k += 16) {
            int s0 = __shfl(myidx, k + 0 + q);
            int s1 = __shfl(myidx, k + 4 + q);
            int s2 = __shfl(myidx, k + 8 + q);
            int s3 = __shfl(myidx, k + 12 + q);
            uint4 u0 = *(const uint4*)(h + (size_t)s0 * 128 + l * 8);
            uint4 u1 = *(const uint4*)(h + (size_t)s1 * 128 + l * 8);
            uint4 u2 = *(const uint4*)(h + (size_t)s2 * 128 + l * 8);
            uint4 u3 = *(const uint4*)(h + (size_t)s3 * 128 + l * 8);
            acc8(a, u0); acc8(a, u1); acc8(a, u2); acc8(a, u3);
        }
        for (; k < cnt; k += 4) {
            int kk = k + q;
            int s = __shfl(myidx, (kk < cnt) ? kk : 0);
            uint4 u = *(const uint4*)(h + (size_t)s * 128 + l * 8);
            if (kk < cnt) acc8(a, u);
        }
    }
    #pragma unroll
    for (int i = 0; i < 8; ++i) {
        a[i] += __shfl_xor(a[i], 32);
        a[i] += __shfl_xor(a[i], 16);
    }
    if (q == 0) {
        const float s = nd[wave];
        const float sn = nsc[wave];
        uint4 o;
        u32 w0, w1;
        w0 = f2bfu(fmaxf(fmaf(a[0], s, b[l * 8 + 0]), 0.f) * sn);
        w1 = f2bfu(fmaxf(fmaf(a[1], s, b[l * 8 + 1]), 0.f) * sn);
        o.x = (w1 << 16) | w0;
        w0 = f2bfu(fmaxf(fmaf(a[2], s, b[l * 8 + 2]), 0.f) * sn);
        w1 = f2bfu(fmaxf(fmaf(a[3], s, b[l * 8 + 3]), 0.f) * sn);
        o.y = (w1 << 16) | w0;
        w0 = f2bfu(fmaxf(fmaf(a[4], s, b[l * 8 + 4]), 0.f) * sn);
        w1 = f2bfu(fmaxf(fmaf(a[5], s, b[l * 8 + 5]), 0.f) * sn);
        o.z = (w1 << 16) | w0;
        w0 = f2bfu(fmaxf(fmaf(a[6], s, b[l * 8 + 6]), 0.f) * sn);
        w1 = f2bfu(fmaxf(fmaf(a[7], s, b[l * 8 + 7]), 0.f) * sn);
        o.w = (w1 << 16) | w0;
        *(uint4*)(out + (size_t)wave * 128 + l * 8) = o;
    }
}

// Gather F=64: 8 lanes/row uint4, 8 edges/step, unroll x4.
__global__ __launch_bounds__(256) void gather64_kernel(const int* __restrict__ row_ptr,
    const int* __restrict__ eidx, const u16* __restrict__ h,
    const float* __restrict__ nd, const float* __restrict__ b,
    float* __restrict__ out, int M)
{
    const int wave = (blockIdx.x * 256 + threadIdx.x) >> 6;
    const int lane = threadIdx.x & 63;
    if (wave >= M) return;
    const int beg = row_ptr[wave];
    const int end = row_ptr[wave + 1];
    const int o = lane >> 3;
    const int l = lane & 7;
    float a[8] = {};
    for (int jb = beg; jb < end; jb += 64) {
        const int cnt = min(64, end - jb);
        int myidx = (jb + lane < end) ? eidx[jb + lane] : 0;
        int k = 0;
        for (; k + 32 <= cnt; k += 32) {
            int s0 = __shfl(myidx, k + 0 + o);
            int s1 = __shfl(myidx, k + 8 + o);
            int s2 = __shfl(myidx, k + 16 + o);
            int s3 = __shfl(myidx, k + 24 + o);
            uint4 u0 = *(const uint4*)(h + (size_t)s0 * 64 + l * 8);
            uint4 u1 = *(const uint4*)(h + (size_t)s1 * 64 + l * 8);
            uint4 u2 = *(const uint4*)(h + (size_t)s2 * 64 + l * 8);
            uint4 u3 = *(const uint4*)(h + (size_t)s3 * 64 + l * 8);
            acc8(a, u0); acc8(a, u1); acc8(a, u2); acc8(a, u3);
        }
        for (; k < cnt; k += 8) {
            int kk = k + o;
            int s = __shfl(myidx, (kk < cnt) ? kk : 0);
            uint4 u = *(const uint4*)(h + (size_t)s * 64 + l * 8);
            if (kk < cnt) acc8(a, u);
        }
    }
    #pragma unroll
    for (int i = 0; i < 8; ++i) {
        a[i] += __shfl_xor(a[i], 32);
        a[i] += __shfl_xor(a[i], 16);
        a[i] += __shfl_xor(a[i], 8);
    }
    if (o == 0) {
        const float s = nd[wave];
        float4 o0, o1;
        o0.x = fmaf(a[0], s, b[l * 8 + 0]);
        o0.y = fmaf(a[1], s, b[l * 8 + 1]);
        o0.z = fmaf(a[2], s, b[l * 8 + 2]);
        o0.w = fmaf(a[3], s, b[l * 8 + 3]);
        o1.x = fmaf(a[4], s, b[l * 8 + 4]);
        o1.y = fmaf(a[5], s, b[l * 8 + 5]);
        o1.z = fmaf(a[6], s, b[l * 8 + 6]);
        o1.w = fmaf(a[7], s, b[l * 8 + 7]);
        *(float4*)(out + (size_t)wave * 64 + l * 8) = o0;
        *(float4*)(out + (size_t)wave * 64 + l * 8 + 4) = o1;
    }
}

extern "C" void kernel_launch(void* const* d_in, const int* in_sizes, int n_in,
                              void* d_out, int out_size, void* d_ws, size_t ws_size,
                              hipStream_t stream) {
    const float* x  = (const float*)d_in[0];   // [M,128] f32
    const int*   ei = (const int*)d_in[1];     // [2,E] int32
    const float* W0 = (const float*)d_in[2];   // [128,128]
    const float* b0 = (const float*)d_in[3];   // [128]
    const float* W1 = (const float*)d_in[4];   // [128,64]
    const float* b1 = (const float*)d_in[5];   // [64]

    const int M = in_sizes[0] / 128;     // 100000
    const int E = in_sizes[1] / 2;       // 3200000
    const int* src = ei;
    const int* dst = ei + E;
    const int W = (M + 3) >> 2;

    char* ws = (char*)d_ws;
    size_t off = 0;
    auto alloc = [&](size_t bytes) {
        void* p = ws + off; off += (bytes + 255) & ~(size_t)255; return p;
    };
    int*   deg_in   = (int*)  alloc((size_t)M * 4);
    float* norm_src = (float*)alloc((size_t)M * 4);
    float* norm_dst = (float*)alloc((size_t)M * 4);
    int*   row_ptr  = (int*)  alloc((size_t)(M + 1) * 4);
    int*   bsum     = (int*)  alloc(256 * 4);
    int*   boff     = (int*)  alloc(256 * 4);
    u16*   Wt0      = (u16*)  alloc(128 * 128 * 2);
    u16*   Wt1      = (u16*)  alloc(64 * 128 * 2);
    int*   eidx     = (int*)  alloc((size_t)E * 4);        // 12.8 MB
    u16*   hbuf     = (u16*)  alloc((size_t)M * 128 * 2);  // 25.6 MB: h0 -> h1
    u16*   out0b    = (u16*)  alloc((size_t)M * 128 * 2);  // 25.6 MB: out0 (bf16, *ns)

    // pd/ps/cum alias hbuf/out0b (38.4MB); dead before gemm0/gather128 write.
    u32* pd  = (u32*)hbuf;
    u32* ps  = pd + (size_t)NCHUNK * W;
    u32* cum = ps + (size_t)NCHUNK * W;

    const int NB = (M + 1023) / 1024;   // 98

    // graph preprocessing (deterministic; no global atomics)
    hist8_kernel<<<2 * NCHUNK, 1024, 0, stream>>>(src, dst, E, M, pd, ps);
    cumreduce_kernel<<<NB, 256, 0, stream>>>(pd, ps, cum, deg_in,
        norm_src, norm_dst, bsum, M);
    scan2_transpose_kernel<<<25, 256, 0, stream>>>(bsum, boff, NB, row_ptr, M,
        W0, W1, Wt0, Wt1);
    scan3_kernel<<<NB, 256, 0, stream>>>(deg_in, boff, row_ptr, M);
    place2_kernel<<<NS * NCHUNK, 256, 0, stream>>>(src, dst, E, M, row_ptr, cum, eidx);

    const int GB = (M + 63) / 64;
    // layer 0: h0 = bf16((x*ns)@W0) ; out0b = bf16(relu(gather(h0)*nd + b0) * ns)
    mfma_gemm_kernel<128, true><<<GB, 256, 0, stream>>>(x, Wt0, norm_src, hbuf, M);
    gather128_kernel<<<(M * 64 + 255) / 256, 256, 0, stream>>>(
        row_ptr, eidx, hbuf, norm_dst, norm_src, b0, out0b, M);

    // layer 1: h1 = bf16(out0b@W1) ; out = gather(h1)*nd + b1
    mfma_gemm_kernel<64, false><<<GB, 256, 0, stream>>>(out0b, Wt1, nullptr, hbuf, M);
    gather64_kernel<<<(M * 64 + 255) / 256, 256, 0, stream>>>(
        row_ptr, eidx, hbuf, norm_dst, b1, (float*)d_out, M);
}